// Round 1
// 362.908 us; speedup vs baseline: 1.0192x; 1.0192x over previous
//
#include <hip/hip_runtime.h>

#define BUCKETS_LOG2 22
#define BUCKET_MASK ((1u << BUCKETS_LOG2) - 1u)
#define BLOCK 256
#define PTS_PER_BLOCK (BLOCK / 2)   // 2 lanes per point

typedef float f32x4 __attribute__((ext_vector_type(4)));

__global__ __launch_bounds__(BLOCK) void hash_trilerp_kernel(
    const float* __restrict__ pts,          // (N,3)
    const float* __restrict__ vf,           // (BUCKETS, 8)
    const unsigned int* __restrict__ primes,// (3,)
    float* __restrict__ out,                // (N,8)
    int n)
{
    __shared__ float sp[3 * PTS_PER_BLOCK];

    const int tid = threadIdx.x;
    const int pbase = blockIdx.x * PTS_PER_BLOCK;

    // Coalesced staging of pts (AoS stride-3) through LDS: 384 floats / block
    {
        const int total = n * 3;
        const int gbase = pbase * 3;
        #pragma unroll
        for (int j = tid; j < 3 * PTS_PER_BLOCK; j += BLOCK) {
            const int g = gbase + j;
            if (g < total) sp[j] = pts[g];
        }
    }
    __syncthreads();

    const int lp = tid >> 1;                 // local point index (0..127)
    const int p  = pbase + lp;               // global point index
    const unsigned int h = (unsigned int)(tid & 1);  // which 16B half of each bucket
    if (p >= n) return;

    const unsigned int p0 = primes[0];
    const unsigned int p1 = primes[1];
    const unsigned int p2 = primes[2];

    // Lane pair (2k, 2k+1) reads the SAME point -> identical hashes, adjacent halves.
    const float px = sp[3 * lp + 0];
    const float py = sp[3 * lp + 1];
    const float pz = sp[3 * lp + 2];

    // q = pts / RES, RES = 1/1024 (exact power of two -> multiply is exact)
    const float qx = px * 1024.0f;
    const float qy = py * 1024.0f;
    const float qz = pz * 1024.0f;

    const float bxf = floorf(qx);
    const float byf = floorf(qy);
    const float bzf = floorf(qz);
    const float fx = qx - bxf, fy = qy - byf, fz = qz - bzf;

    const unsigned int bx = (unsigned int)(int)bxf;
    const unsigned int by = (unsigned int)(int)byf;
    const unsigned int bz = (unsigned int)(int)bzf;

    // hash partials (uint32 wraparound semantics, matches reference)
    unsigned int hx[2], hy[2], hz[2];
    hx[0] = bx * p0; hx[1] = hx[0] + p0;
    hy[0] = by * p1; hy[1] = hy[0] + p1;
    hz[0] = bz * p2; hz[1] = hz[0] + p2;

    // ---- Phase 1: 8 bucket BYTE offsets (uint32; table = 128 MB < 2^32),
    //      plus this lane's 16B half. Lanes 2k/2k+1 -> contiguous 32B pair
    //      inside ONE load instruction -> coalesced to a single 32B request. ----
    const unsigned int hoff = h << 4;
    unsigned int boff[8];
    #pragma unroll
    for (int c = 0; c < 8; ++c) {
        const int cx = c & 1, cy = (c >> 1) & 1, cz = (c >> 2) & 1;
        const unsigned int vid = (hx[cx] + hy[cy] + hz[cz]) & BUCKET_MASK;
        boff[c] = (vid << 5) | hoff;   // vid*32 bytes + half*16
    }

    // ---- Phase 2: all 8 dwordx4 loads in flight (saddr form), one vmcnt(0) ----
    f32x4 f0, f1, f2, f3, f4, f5, f6, f7;
    #define GLD(dst, off) \
        asm volatile("global_load_dwordx4 %0, %1, %2" \
                     : "=v"(dst) : "v"(off), "s"(vf))
    GLD(f0, boff[0]);
    GLD(f1, boff[1]);
    GLD(f2, boff[2]);
    GLD(f3, boff[3]);
    GLD(f4, boff[4]);
    GLD(f5, boff[5]);
    GLD(f6, boff[6]);
    GLD(f7, boff[7]);
    #undef GLD

    // ---- Weights while loads are in flight ----
    const float wx[2] = { 1.0f - fx, fx };
    const float wy[2] = { 1.0f - fy, fy };
    const float wz[2] = { 1.0f - fz, fz };

    float w[8];
    #pragma unroll
    for (int c = 0; c < 8; ++c) {
        const int cx = c & 1, cy = (c >> 1) & 1, cz = (c >> 2) & 1;
        w[c] = wx[cx] * wy[cy] * wz[cz];
    }

    // Single drain; "+v" ties force every consumer below this point.
    asm volatile("s_waitcnt vmcnt(0)"
                 : "+v"(f0), "+v"(f1), "+v"(f2), "+v"(f3),
                   "+v"(f4), "+v"(f5), "+v"(f6), "+v"(f7)
                 :: "memory");

    // ---- Phase 3: accumulate this lane's 4 features ----
    f32x4 a = { 0.f, 0.f, 0.f, 0.f };
    a += w[0] * f0;
    a += w[1] * f1;
    a += w[2] * f2;
    a += w[3] * f3;
    a += w[4] * f4;
    a += w[5] * f5;
    a += w[6] * f6;
    a += w[7] * f7;

    // Streaming store: 64 lanes x 16B = fully contiguous 1KB per instruction
    f32x4* __restrict__ o4 = (f32x4*)out;
    __builtin_nontemporal_store(a, &o4[(size_t)p * 2u + h]);
}

extern "C" void kernel_launch(void* const* d_in, const int* in_sizes, int n_in,
                              void* d_out, int out_size, void* d_ws, size_t ws_size,
                              hipStream_t stream) {
    const float* pts            = (const float*)d_in[0];
    const float* vf             = (const float*)d_in[1];
    const unsigned int* primes  = (const unsigned int*)d_in[2];
    float* out                  = (float*)d_out;

    const int n = in_sizes[0] / 3;   // N_PTS
    const int grid = (n + PTS_PER_BLOCK - 1) / PTS_PER_BLOCK;
    hash_trilerp_kernel<<<grid, BLOCK, 0, stream>>>(pts, vf, primes, out, n);
}